// Round 8
// baseline (936.324 us; speedup 1.0000x reference)
//
#include <hip/hip_runtime.h>

// SR-GNN session model, MI355X (gfx950). Inputs fp32/int32, output fp32.
// r8: (1) session kernel restructured: 8 sessions/block, thread=(sess,col d),
//     register-resident node state, k-blocked GRU gates, shfl alpha-reduce.
//     (2) score kernel: 4 v-columns per thread (x4 sg-LDS amortization),
//     lane-consecutive loads/stores, nontemporal output stream.
//
// ws layout: [0) s_g fp32 : 4096 x 32 f32  (512 KB)

#define B_BATCH 4096
#define N_NODE  16
#define L_SEQ   20
#define D_DIM   32
#define NV_OUT  49999

typedef float f32x4 __attribute__((ext_vector_type(4)));

__device__ __forceinline__ float sigf(float x) {
    return 1.0f / (1.0f + __expf(-x));
}

// ---------------------------------------------------------------- kernel 1
// 8 sessions per block; 256 threads; thread = (s = tid>>5, d = tid&31).
// LDS: h2 [8][16][32] (h, then h_new), bufA/bufB (A -> ii/io -> seq).
__global__ __launch_bounds__(256) void session2_kernel(
    const int*   __restrict__ alias_inputs,  // [B,20]
    const float* __restrict__ A,             // [B,16,32]
    const int*   __restrict__ items,         // [B,16]
    const int*   __restrict__ mask,          // [B,20]
    const float* __restrict__ emb,           // [V,32]
    const float* __restrict__ w_ih,          // [96,64]
    const float* __restrict__ w_hh,          // [96,32]
    const float* __restrict__ b_ih, const float* __restrict__ b_hh,
    const float* __restrict__ b_iah, const float* __restrict__ b_oah,
    const float* __restrict__ w_ein, const float* __restrict__ b_ein,
    const float* __restrict__ w_eout, const float* __restrict__ b_eout,
    const float* __restrict__ w1, const float* __restrict__ b1,
    const float* __restrict__ w2, const float* __restrict__ b2,
    const float* __restrict__ w3,
    float* __restrict__ sg_out)              // [B,32] fp32 (ws)
{
    const int tid  = threadIdx.x;
    const int s    = tid >> 5;
    const int d    = tid & 31;
    const int sess = blockIdx.x * 8 + s;

    __shared__ float h2  [8][N_NODE][D_DIM];   // 16 KB
    __shared__ float bufA[8][N_NODE][D_DIM];   // 16 KB
    __shared__ float bufB[8][N_NODE][D_DIM];   // 16 KB

    // ---- P0: stage h (emb gather) and A, both coalesced over d
    #pragma unroll
    for (int n = 0; n < N_NODE; ++n) {
        const int it = items[sess * N_NODE + n];
        h2[s][n][d]   = emb[(size_t)it * D_DIM + d];
        bufA[s][n][d] = A[(size_t)sess * 512 + n * 32 + d];
    }
    __syncthreads();

    // ---- P1: ni[n] = node_in[n][d], no[n] = node_out[n][d] (registers)
    float ni[N_NODE], no[N_NODE];
    {
        float wein[32], weout[32];
        #pragma unroll
        for (int k = 0; k < 32; ++k) {
            wein[k]  = w_ein[k * 32 + d];
            weout[k] = w_eout[k * 32 + d];
        }
        const float be_i = b_ein[d], be_o = b_eout[d];
        #pragma unroll
        for (int n = 0; n < N_NODE; ++n) {
            const float* hp = &h2[s][n][0];
            float ai = be_i, ao = be_o;
            #pragma unroll
            for (int k = 0; k < 32; ++k) {
                const float hv = hp[k];
                ai += hv * wein[k];
                ao += hv * weout[k];
            }
            ni[n] = ai; no[n] = ao;
        }
    }

    // ---- P2: ii[n], io[n] from adjacency (bufA still holds A)
    float ii[N_NODE], io[N_NODE];
    {
        const float bi = b_iah[d], bo = b_oah[d];
        #pragma unroll
        for (int n = 0; n < N_NODE; ++n) {
            const float* ap = &bufA[s][n][0];
            float x = bi, y = bo;
            #pragma unroll
            for (int m = 0; m < N_NODE; ++m) {
                x += ap[m]      * ni[m];
                y += ap[16 + m] * no[m];
            }
            ii[n] = x; io[n] = y;
        }
    }
    __syncthreads();                      // all done reading A
    #pragma unroll
    for (int n = 0; n < N_NODE; ++n) {    // transpose ii/io into LDS
        bufA[s][n][d] = ii[n];
        bufB[s][n][d] = io[n];
    }
    __syncthreads();                      // ii/io visible

    // ---- P3: GRU gate sums, k-blocked (8 k per block)
    float rs[N_NODE], is_[N_NODE], ins[N_NODE], hns[N_NODE];
    {
        const float br  = b_ih[d]      + b_hh[d];
        const float bi2 = b_ih[32 + d] + b_hh[32 + d];
        const float bni = b_ih[64 + d];
        const float bnh = b_hh[64 + d];
        #pragma unroll
        for (int n = 0; n < N_NODE; ++n) {
            rs[n] = br; is_[n] = bi2; ins[n] = bni; hns[n] = bnh;
        }
    }
    #pragma unroll
    for (int kb = 0; kb < 4; ++kb) {
        const int k0 = kb * 8;
        // w_ih rows d (reset), 32+d (input), 64+d (new); in-half and out-half
        const f32x4 wrA = *(const f32x4*)&w_ih[(d)      * 64 + k0];
        const f32x4 wrB = *(const f32x4*)&w_ih[(d)      * 64 + k0 + 4];
        const f32x4 wrC = *(const f32x4*)&w_ih[(d)      * 64 + 32 + k0];
        const f32x4 wrD = *(const f32x4*)&w_ih[(d)      * 64 + 32 + k0 + 4];
        const f32x4 wiA = *(const f32x4*)&w_ih[(32 + d) * 64 + k0];
        const f32x4 wiB = *(const f32x4*)&w_ih[(32 + d) * 64 + k0 + 4];
        const f32x4 wiC = *(const f32x4*)&w_ih[(32 + d) * 64 + 32 + k0];
        const f32x4 wiD = *(const f32x4*)&w_ih[(32 + d) * 64 + 32 + k0 + 4];
        const f32x4 wnA = *(const f32x4*)&w_ih[(64 + d) * 64 + k0];
        const f32x4 wnB = *(const f32x4*)&w_ih[(64 + d) * 64 + k0 + 4];
        const f32x4 wnC = *(const f32x4*)&w_ih[(64 + d) * 64 + 32 + k0];
        const f32x4 wnD = *(const f32x4*)&w_ih[(64 + d) * 64 + 32 + k0 + 4];
        const f32x4 hrA = *(const f32x4*)&w_hh[(d)      * 32 + k0];
        const f32x4 hrB = *(const f32x4*)&w_hh[(d)      * 32 + k0 + 4];
        const f32x4 hiA = *(const f32x4*)&w_hh[(32 + d) * 32 + k0];
        const f32x4 hiB = *(const f32x4*)&w_hh[(32 + d) * 32 + k0 + 4];
        const f32x4 hnA = *(const f32x4*)&w_hh[(64 + d) * 32 + k0];
        const f32x4 hnB = *(const f32x4*)&w_hh[(64 + d) * 32 + k0 + 4];
        #pragma unroll
        for (int n = 0; n < N_NODE; ++n) {
            const f32x4 ia = *(const f32x4*)&bufA[s][n][k0];
            const f32x4 ib = *(const f32x4*)&bufA[s][n][k0 + 4];
            const f32x4 oa = *(const f32x4*)&bufB[s][n][k0];
            const f32x4 ob = *(const f32x4*)&bufB[s][n][k0 + 4];
            const f32x4 ha = *(const f32x4*)&h2[s][n][k0];
            const f32x4 hb = *(const f32x4*)&h2[s][n][k0 + 4];
            float r = rs[n], i2 = is_[n], in_ = ins[n], hn_ = hns[n];
            #pragma unroll
            for (int j = 0; j < 4; ++j) {
                r   += ia[j] * wrA[j] + oa[j] * wrC[j] + ha[j] * hrA[j];
                r   += ib[j] * wrB[j] + ob[j] * wrD[j] + hb[j] * hrB[j];
                i2  += ia[j] * wiA[j] + oa[j] * wiC[j] + ha[j] * hiA[j];
                i2  += ib[j] * wiB[j] + ob[j] * wiD[j] + hb[j] * hiB[j];
                in_ += ia[j] * wnA[j] + oa[j] * wnC[j];
                in_ += ib[j] * wnB[j] + ob[j] * wnD[j];
                hn_ += ha[j] * hnA[j] + hb[j] * hnB[j];
            }
            rs[n] = r; is_[n] = i2; ins[n] = in_; hns[n] = hn_;
        }
    }

    // ---- P4: GRU nonlinearity, h update
    float hnew[N_NODE];
    #pragma unroll
    for (int n = 0; n < N_NODE; ++n) {
        const float rg = sigf(rs[n]);
        const float ig = sigf(is_[n]);
        const float ng = tanhf(ins[n] + rg * hns[n]);
        const float hp = h2[s][n][d];
        hnew[n] = ng + ig * (hp - ng);
    }
    __syncthreads();                      // all done reading old h / ii / io
    #pragma unroll
    for (int n = 0; n < N_NODE; ++n) h2[s][n][d] = hnew[n];
    __syncthreads();                      // h_new visible

    // ---- P5: seq gather into bufA(t<16)/bufB(t>=16)
    int al[L_SEQ], mk[L_SEQ];
    #pragma unroll
    for (int t = 0; t < L_SEQ; ++t) {
        al[t] = alias_inputs[sess * L_SEQ + t];
        mk[t] = mask[sess * L_SEQ + t];
    }
    int last = -1;
    #pragma unroll
    for (int t = 0; t < L_SEQ; ++t) last += mk[t];
    #pragma unroll
    for (int t = 0; t < L_SEQ; ++t) {
        const float v = h2[s][al[t]][d];
        if (t < 16) bufA[s][t][d] = v;
        else        bufB[s][t - 16][d] = v;
    }
    __syncthreads();                      // seq visible

    // ---- P6: q1[d]
    float q1 = b1[d];
    {
        float w1c[32];
        #pragma unroll
        for (int k = 0; k < 32; ++k) w1c[k] = w1[k * 32 + d];
        const float* sl = (last < 16) ? &bufA[s][last][0] : &bufB[s][last - 16][0];
        #pragma unroll
        for (int k = 0; k < 32; ++k) q1 += sl[k] * w1c[k];
    }

    // ---- P7/P8: alpha via width-32 shfl reduce, accumulate s_g
    {
        float w2c[32];
        #pragma unroll
        for (int k = 0; k < 32; ++k) w2c[k] = w2[k * 32 + d];
        const float b2d = b2[d], w3d = w3[d];
        float sgacc = 0.0f;
        #pragma unroll
        for (int t = 0; t < L_SEQ; ++t) {
            const float* sp = (t < 16) ? &bufA[s][t][0] : &bufB[s][t - 16][0];
            float q2 = b2d;
            #pragma unroll
            for (int k = 0; k < 32; ++k) q2 += sp[k] * w2c[k];
            float val = sigf(q1 + q2) * w3d;
            val += __shfl_xor(val, 1, 32);
            val += __shfl_xor(val, 2, 32);
            val += __shfl_xor(val, 4, 32);
            val += __shfl_xor(val, 8, 32);
            val += __shfl_xor(val, 16, 32);
            const float a = val * (float)mk[t];
            sgacc += a * sp[d];
        }
        sg_out[sess * D_DIM + d] = sgacc;
    }
}

// ---------------------------------------------------------------- kernel 2
// scores[b, v] = sum_d s_g[b,d] * emb[1+v, d]
// 256 threads; thread handles 4 v-columns (v_i = by*1024 + i*256 + tid) and
// 16 b-rows; sg tile in LDS, read once per row and reused x4.
// Grid: (B/16 = 256 [x, fastest -> emb L2 reuse], ceil(49999/1024) = 49 [y]).
__global__ __launch_bounds__(256) void score2_kernel(
    const float* __restrict__ sg,    // [4096, 32] f32 (ws)
    const float* __restrict__ emb,   // [50000, 32] f32
    float* __restrict__ out)         // [4096, 49999] f32
{
    __shared__ float sg_s[16][32];
    const int tid = threadIdx.x;
    const int b0  = blockIdx.x * 16;
    const int vb  = blockIdx.y * 1024;

    if (tid < 128) {
        reinterpret_cast<f32x4*>(&sg_s[0][0])[tid] =
            reinterpret_cast<const f32x4*>(&sg[(size_t)b0 * D_DIM])[tid];
    }
    __syncthreads();

    int v[4];
    float e[4][32];
    #pragma unroll
    for (int i = 0; i < 4; ++i) {
        v[i] = vb + i * 256 + tid;
        const int vc = (v[i] < NV_OUT) ? v[i] : (NV_OUT - 1);   // clamp loads
        const f32x4* ep = reinterpret_cast<const f32x4*>(&emb[(size_t)(1 + vc) * D_DIM]);
        #pragma unroll
        for (int c = 0; c < 8; ++c)
            reinterpret_cast<f32x4*>(&e[i][0])[c] = ep[c];
    }

    #pragma unroll
    for (int r = 0; r < 16; ++r) {
        const float* srow = &sg_s[r][0];
        float a0 = 0.0f, a1 = 0.0f, a2 = 0.0f, a3 = 0.0f;
        #pragma unroll
        for (int k = 0; k < 32; ++k) {
            const float sv = srow[k];
            a0 += e[0][k] * sv;
            a1 += e[1][k] * sv;
            a2 += e[2][k] * sv;
            a3 += e[3][k] * sv;
        }
        float* op = out + (size_t)(b0 + r) * NV_OUT;
        if (v[0] < NV_OUT) __builtin_nontemporal_store(a0, op + v[0]);
        if (v[1] < NV_OUT) __builtin_nontemporal_store(a1, op + v[1]);
        if (v[2] < NV_OUT) __builtin_nontemporal_store(a2, op + v[2]);
        if (v[3] < NV_OUT) __builtin_nontemporal_store(a3, op + v[3]);
    }
}

// ---------------------------------------------------------------- launch
extern "C" void kernel_launch(void* const* d_in, const int* in_sizes, int n_in,
                              void* d_out, int out_size, void* d_ws, size_t ws_size,
                              hipStream_t stream)
{
    const int*   alias_inputs = (const int*)  d_in[0];
    const float* A      = (const float*)d_in[1];
    const int*   items  = (const int*)  d_in[2];
    const int*   mask   = (const int*)  d_in[3];
    const float* emb    = (const float*)d_in[4];
    const float* w_ih   = (const float*)d_in[5];
    const float* w_hh   = (const float*)d_in[6];
    const float* b_ih   = (const float*)d_in[7];
    const float* b_hh   = (const float*)d_in[8];
    const float* b_iah  = (const float*)d_in[9];
    const float* b_oah  = (const float*)d_in[10];
    const float* w_ein  = (const float*)d_in[11];
    const float* b_ein  = (const float*)d_in[12];
    const float* w_eout = (const float*)d_in[13];
    const float* b_eout = (const float*)d_in[14];
    const float* w1     = (const float*)d_in[15];
    const float* b1     = (const float*)d_in[16];
    const float* w2     = (const float*)d_in[17];
    const float* b2     = (const float*)d_in[18];
    const float* w3     = (const float*)d_in[19];

    float* sg  = (float*)d_ws;                     // 4096*32 f32
    float* out = (float*)d_out;                    // FP32 output

    hipLaunchKernelGGL(session2_kernel, dim3(B_BATCH / 8), dim3(256), 0, stream,
                       alias_inputs, A, items, mask, emb,
                       w_ih, w_hh, b_ih, b_hh, b_iah, b_oah,
                       w_ein, b_ein, w_eout, b_eout,
                       w1, b1, w2, b2, w3, sg);

    const int nvt = (NV_OUT + 1023) / 1024;   // 49
    hipLaunchKernelGGL(score2_kernel, dim3(B_BATCH / 16, nvt), dim3(256), 0, stream,
                       sg, emb, out);
}

// Round 9
// 589.447 us; speedup vs baseline: 1.5885x; 1.5885x over previous
//
#include <hip/hip_runtime.h>

// SR-GNN session model, MI355X (gfx950). Inputs fp32/int32, output fp32.
// r9: session reverted to r6-proven form (r8's register-column variant hit the
// 256-VGPR cap and spilled 1.6 GB of scratch -> 554 us).
// score3: emb tile staged to LDS TRANSPOSED with coalesced global loads
// (r6-r8 used per-lane scattered emb rows: 64 L1-line txns per load inst ->
// ~380 us load-bound). Per-thread v-column now reads LDS conflict-free;
// sg rows via block-uniform scalar loads; plain (cached) stores.
//
// ws layout: [0) s_g fp32 : 4096 x 32 f32  (512 KB)

#define B_BATCH 4096
#define N_NODE  16
#define L_SEQ   20
#define D_DIM   32
#define NV_OUT  49999

typedef float f32x4 __attribute__((ext_vector_type(4)));

__device__ __forceinline__ float sigf(float x) {
    return 1.0f / (1.0f + __expf(-x));
}

// ---------------------------------------------------------------- kernel 1
// One block per session. All per-sample tensors live in LDS (fp32).
// VERBATIM r6 passing baseline.
__global__ __launch_bounds__(256) void session_kernel(
    const int*   __restrict__ alias_inputs,  // [B,L]
    const float* __restrict__ A,             // [B,N,2N]
    const int*   __restrict__ items,         // [B,N]
    const int*   __restrict__ mask,          // [B,L]
    const float* __restrict__ emb,           // [V,D]
    const float* __restrict__ w_ih,          // [3D,2D]
    const float* __restrict__ w_hh,          // [3D,D]
    const float* __restrict__ b_ih, const float* __restrict__ b_hh,
    const float* __restrict__ b_iah, const float* __restrict__ b_oah,
    const float* __restrict__ w_ein, const float* __restrict__ b_ein,
    const float* __restrict__ w_eout, const float* __restrict__ b_eout,
    const float* __restrict__ w1, const float* __restrict__ b1,
    const float* __restrict__ w2, const float* __restrict__ b2,
    const float* __restrict__ w3,
    float* __restrict__ sg_out)              // [B,D] fp32 (ws)
{
    const int b   = blockIdx.x;
    const int tid = threadIdx.x;

    __shared__ float h_s [N_NODE][D_DIM];
    __shared__ float A_s [N_NODE][2 * N_NODE];
    __shared__ float ni_s[N_NODE][D_DIM];
    __shared__ float no_s[N_NODE][D_DIM];
    __shared__ float ii_s[N_NODE][D_DIM];
    __shared__ float io_s[N_NODE][D_DIM];
    __shared__ float gi_s[N_NODE][3 * D_DIM];
    __shared__ float gh_s[N_NODE][3 * D_DIM];
    __shared__ float seq_s[L_SEQ][D_DIM];
    __shared__ float q1_s[D_DIM];
    __shared__ float alpha_s[L_SEQ];
    __shared__ int   last_s;

    // P0: gather item embeddings, load adjacency
    for (int idx = tid; idx < N_NODE * D_DIM; idx += 256) {
        const int n = idx >> 5, d = idx & 31;
        const int it = items[b * N_NODE + n];
        h_s[n][d] = emb[(size_t)it * D_DIM + d];
        A_s[n][d] = A[(size_t)b * 512 + idx];
    }
    __syncthreads();

    // P1: node_in = h @ w_ein + b_ein ; node_out = h @ w_eout + b_eout
    for (int idx = tid; idx < N_NODE * D_DIM; idx += 256) {
        const int n = idx >> 5, d = idx & 31;
        float ai = b_ein[d], ao = b_eout[d];
        #pragma unroll
        for (int k = 0; k < D_DIM; ++k) {
            const float hv = h_s[n][k];
            ai += hv * w_ein[k * D_DIM + d];
            ao += hv * w_eout[k * D_DIM + d];
        }
        ni_s[n][d] = ai;
        no_s[n][d] = ao;
    }
    __syncthreads();

    // P2: input_in = A_in @ node_in + b_iah ; input_out = A_out @ node_out + b_oah
    for (int idx = tid; idx < N_NODE * D_DIM; idx += 256) {
        const int n = idx >> 5, d = idx & 31;
        float ii = b_iah[d], io = b_oah[d];
        #pragma unroll
        for (int m = 0; m < N_NODE; ++m) {
            ii += A_s[n][m]          * ni_s[m][d];
            io += A_s[n][N_NODE + m] * no_s[m][d];
        }
        ii_s[n][d] = ii;
        io_s[n][d] = io;
    }
    __syncthreads();

    // P3: gi = [input_in, input_out] @ w_ih^T + b_ih ; gh = h @ w_hh^T + b_hh
    for (int idx = tid; idx < N_NODE * 96; idx += 256) {
        const int n = idx / 96, j = idx % 96;
        float gi = b_ih[j], gh = b_hh[j];
        #pragma unroll
        for (int k = 0; k < D_DIM; ++k) {
            gi += ii_s[n][k] * w_ih[j * 64 + k];
            gi += io_s[n][k] * w_ih[j * 64 + 32 + k];
            gh += h_s[n][k]  * w_hh[j * 32 + k];
        }
        gi_s[n][j] = gi;
        gh_s[n][j] = gh;
    }
    __syncthreads();

    // P4: GRU cell, update h in place
    for (int idx = tid; idx < N_NODE * D_DIM; idx += 256) {
        const int n = idx >> 5, d = idx & 31;
        const float i_r = gi_s[n][d],      h_r = gh_s[n][d];
        const float i_i = gi_s[n][32 + d], h_i = gh_s[n][32 + d];
        const float i_n = gi_s[n][64 + d], h_n = gh_s[n][64 + d];
        const float rg = sigf(i_r + h_r);
        const float ig = sigf(i_i + h_i);
        const float x  = i_n + rg * h_n;
        const float ax = fabsf(x);
        const float e  = __expf(2.0f * ax);
        const float ng = copysignf(1.0f - 2.0f / (e + 1.0f), x);
        const float hv = h_s[n][d];
        h_s[n][d] = ng + ig * (hv - ng);
    }
    __syncthreads();

    // P5: seq gather + last index
    for (int idx = tid; idx < L_SEQ * D_DIM; idx += 256) {
        const int t = idx >> 5, d = idx & 31;
        const int a = alias_inputs[b * L_SEQ + t];
        seq_s[t][d] = h_s[a][d];
    }
    if (tid == 0) {
        int s = 0;
        for (int t = 0; t < L_SEQ; ++t) s += mask[b * L_SEQ + t];
        last_s = s - 1;
    }
    __syncthreads();

    // P6: q1 = ht @ w1 + b1
    if (tid < D_DIM) {
        const int d = tid;
        const int lt = last_s;
        float acc = b1[d];
        #pragma unroll
        for (int k = 0; k < D_DIM; ++k) acc += seq_s[lt][k] * w1[k * D_DIM + d];
        q1_s[d] = acc;
    }
    __syncthreads();

    // P7: alpha[t] = sum_d sigmoid(q1[d] + q2[t,d]) * w3[d]
    float* tmp = &gi_s[0][0];
    for (int idx = tid; idx < L_SEQ * D_DIM; idx += 256) {
        const int t = idx >> 5, d = idx & 31;
        float q2 = b2[d];
        #pragma unroll
        for (int k = 0; k < D_DIM; ++k) q2 += seq_s[t][k] * w2[k * D_DIM + d];
        tmp[idx] = sigf(q1_s[d] + q2) * w3[d];
    }
    __syncthreads();
    if (tid < L_SEQ) {
        float a = 0.0f;
        #pragma unroll
        for (int d = 0; d < D_DIM; ++d) a += tmp[tid * D_DIM + d];
        alpha_s[tid] = a * (float)mask[b * L_SEQ + tid];
    }
    __syncthreads();

    // P8: s_g[d] = sum_t alpha[t] * seq[t,d]
    if (tid < D_DIM) {
        const int d = tid;
        float acc = 0.0f;
        #pragma unroll
        for (int t = 0; t < L_SEQ; ++t) acc += alpha_s[t] * seq_s[t][d];
        sg_out[b * D_DIM + d] = acc;
    }
}

// ---------------------------------------------------------------- kernel 2
// scores[b, v] = sum_d s_g[b,d] * emb[1+v, d]
// Block: 16 b-rows x 256 v-cols, 256 threads (thread = one v-col).
// emb tile staged to LDS TRANSPOSED (coalesced 1KB/wave global loads;
// +1-padded rows -> conflict-free column reads). sg via block-uniform
// scalar loads (SGPR operands into v_fmac).
// Grid: (x = 256 b-tiles [fastest -> 256 blocks share one emb tile],
//        y = 196 v-tiles).
__global__ __launch_bounds__(256) void score3_kernel(
    const float* __restrict__ sg,    // [4096, 32] f32 (ws)
    const float* __restrict__ emb,   // [50000, 32] f32
    float* __restrict__ out)         // [4096, 49999] f32
{
    __shared__ float eT[D_DIM][257];   // transposed emb tile, 32.9 KB
    const int tid = threadIdx.x;
    const int b0  = blockIdx.x * 16;
    const int v0  = blockIdx.y * 256;

    // stage: flat f32x4 chunk id f = r*8 + c (r = tile row, c = 16B chunk);
    // consecutive lanes -> consecutive 16B chunks -> 1KB contiguous per wave.
    #pragma unroll
    for (int i = 0; i < 8; ++i) {
        const int f = i * 256 + tid;
        const int r = f >> 3, c = f & 7;
        int grow = 1 + v0 + r;
        if (grow > NV_OUT) grow = NV_OUT;          // clamp: valid emb row
        const f32x4 ev = *reinterpret_cast<const f32x4*>(
            &emb[(size_t)grow * D_DIM + c * 4]);
        eT[c * 4 + 0][r] = ev[0];
        eT[c * 4 + 1][r] = ev[1];
        eT[c * 4 + 2][r] = ev[2];
        eT[c * 4 + 3][r] = ev[3];
    }
    __syncthreads();

    // my v-column into registers (consecutive-lane LDS reads, conflict-free)
    float e[32];
    #pragma unroll
    for (int k = 0; k < 32; ++k) e[k] = eT[k][tid];

    const int  v  = v0 + tid;
    const bool ok = (v < NV_OUT);

    #pragma unroll
    for (int r = 0; r < 16; ++r) {
        const float* sr = sg + (size_t)(b0 + r) * D_DIM;   // block-uniform
        float acc = 0.0f;
        #pragma unroll
        for (int k = 0; k < 32; ++k) acc += e[k] * sr[k];
        if (ok) out[(size_t)(b0 + r) * NV_OUT + v] = acc;
    }
}

// ---------------------------------------------------------------- launch
extern "C" void kernel_launch(void* const* d_in, const int* in_sizes, int n_in,
                              void* d_out, int out_size, void* d_ws, size_t ws_size,
                              hipStream_t stream)
{
    const int*   alias_inputs = (const int*)  d_in[0];
    const float* A      = (const float*)d_in[1];
    const int*   items  = (const int*)  d_in[2];
    const int*   mask   = (const int*)  d_in[3];
    const float* emb    = (const float*)d_in[4];
    const float* w_ih   = (const float*)d_in[5];
    const float* w_hh   = (const float*)d_in[6];
    const float* b_ih   = (const float*)d_in[7];
    const float* b_hh   = (const float*)d_in[8];
    const float* b_iah  = (const float*)d_in[9];
    const float* b_oah  = (const float*)d_in[10];
    const float* w_ein  = (const float*)d_in[11];
    const float* b_ein  = (const float*)d_in[12];
    const float* w_eout = (const float*)d_in[13];
    const float* b_eout = (const float*)d_in[14];
    const float* w1     = (const float*)d_in[15];
    const float* b1     = (const float*)d_in[16];
    const float* w2     = (const float*)d_in[17];
    const float* b2     = (const float*)d_in[18];
    const float* w3     = (const float*)d_in[19];

    float* sg  = (float*)d_ws;                     // 4096*32 f32
    float* out = (float*)d_out;                    // FP32 output

    hipLaunchKernelGGL(session_kernel, dim3(B_BATCH), dim3(256), 0, stream,
                       alias_inputs, A, items, mask, emb,
                       w_ih, w_hh, b_ih, b_hh, b_iah, b_oah,
                       w_ein, b_ein, w_eout, b_eout,
                       w1, b1, w2, b2, w3, sg);

    const int nvt = (NV_OUT + 255) / 256;   // 196
    hipLaunchKernelGGL(score3_kernel, dim3(B_BATCH / 16, nvt), dim3(256), 0, stream,
                       sg, emb, out);
}

// Round 10
// 407.371 us; speedup vs baseline: 2.2985x; 1.4470x over previous
//
#include <hip/hip_runtime.h>

// SR-GNN session model, MI355X (gfx950). Inputs fp32/int32, output fp32.
// r10: session P3's lane-scattered GLOBAL weight reads (64 cache lines per
// wave-inst; ~430 us of the 589 total) replaced by LDS-staged weights with
// pad-66/34 rows (bank=(2d+k)%32 -> conflict-free) + fused gate/nonlinearity
// phase; thread=(g,d) handles nodes {g,g+8} so weight reads broadcast across
// the wave. Score3 (r9, coalesced emb staging) unchanged.
//
// ws layout: [0) s_g fp32 : 4096 x 32 f32  (512 KB)

#define B_BATCH 4096
#define N_NODE  16
#define L_SEQ   20
#define D_DIM   32
#define NV_OUT  49999

typedef float f32x4 __attribute__((ext_vector_type(4)));

__device__ __forceinline__ float sigf(float x) {
    return 1.0f / (1.0f + __expf(-x));
}

// ---------------------------------------------------------------- kernel 1
// One block per session; 256 threads = 8 node-groups x 32 d-lanes.
// Weights LDS-resident; all hot-loop accesses are conflict-free LDS.
__global__ __launch_bounds__(256) void session3_kernel(
    const int*   __restrict__ alias_inputs,  // [B,20]
    const float* __restrict__ A,             // [B,16,32]
    const int*   __restrict__ items,         // [B,16]
    const int*   __restrict__ mask,          // [B,20]
    const float* __restrict__ emb,           // [V,32]
    const float* __restrict__ w_ih,          // [96,64]
    const float* __restrict__ w_hh,          // [96,32]
    const float* __restrict__ b_ih, const float* __restrict__ b_hh,
    const float* __restrict__ b_iah, const float* __restrict__ b_oah,
    const float* __restrict__ w_ein, const float* __restrict__ b_ein,
    const float* __restrict__ w_eout, const float* __restrict__ b_eout,
    const float* __restrict__ w1, const float* __restrict__ b1,
    const float* __restrict__ w2, const float* __restrict__ b2,
    const float* __restrict__ w3,
    float* __restrict__ sg_out)              // [B,32] fp32 (ws)
{
    const int b   = blockIdx.x;
    const int tid = threadIdx.x;
    const int g   = tid >> 5;      // node group 0..7
    const int d   = tid & 31;      // feature column
    const int n0  = g, n1 = g + 8;

    __shared__ float h_s [N_NODE][D_DIM];     // 2 KB
    __shared__ float A_s [N_NODE][2 * N_NODE];// 2 KB
    __shared__ float ni_s[N_NODE][D_DIM];     // 2 KB (later: seq rows 0-15)
    __shared__ float no_s[N_NODE][D_DIM];     // 2 KB (later: seq rows 16-19)
    __shared__ float ii_s[N_NODE][D_DIM];     // 2 KB (later: P7 tmp 0-15)
    __shared__ float io_s[N_NODE][D_DIM];     // 2 KB (later: P7 tmp 16-19)
    __shared__ float wih_s[96][66];           // 25.3 KB, pad 66: bank=(2d+k)%32
    __shared__ float whh_s[96][34];           // 13.1 KB, pad 34: same property
    __shared__ float q1_s[D_DIM];
    __shared__ float alpha_s[L_SEQ];
    __shared__ int   last_s;                  // total ~49.8 KB -> 3 blocks/CU

    // ---- P0: stage h (emb gather), A, and weights (all coalesced)
    for (int idx = tid; idx < 512; idx += 256) {
        const int n = idx >> 5, dd = idx & 31;
        const int it = items[b * N_NODE + n];
        h_s[n][dd] = emb[(size_t)it * D_DIM + dd];
        A_s[n][dd] = A[(size_t)b * 512 + idx];
    }
    for (int f = tid; f < 96 * 64; f += 256) wih_s[f >> 6][f & 63] = w_ih[f];
    for (int f = tid; f < 96 * 32; f += 256) whh_s[f >> 5][f & 31] = w_hh[f];
    __syncthreads();

    // ---- P1: node_in/node_out for n0, n1 (w_ein/w_eout coalesced L1-hit)
    float ai0 = b_ein[d], ao0 = b_eout[d];
    float ai1 = ai0,      ao1 = ao0;
    #pragma unroll
    for (int k = 0; k < 32; ++k) {
        const float we = w_ein[k * 32 + d], wo = w_eout[k * 32 + d];
        const float h0 = h_s[n0][k], h1 = h_s[n1][k];
        ai0 += h0 * we; ai1 += h1 * we;
        ao0 += h0 * wo; ao1 += h1 * wo;
    }
    ni_s[n0][d] = ai0; ni_s[n1][d] = ai1;
    no_s[n0][d] = ao0; no_s[n1][d] = ao1;
    __syncthreads();

    // ---- P2: adjacency message passing
    float iv0 = b_iah[d], ov0 = b_oah[d];
    float iv1 = iv0,      ov1 = ov0;
    #pragma unroll
    for (int m = 0; m < N_NODE; ++m) {
        const float nim = ni_s[m][d], nom = no_s[m][d];
        iv0 += A_s[n0][m]          * nim;
        iv1 += A_s[n1][m]          * nim;
        ov0 += A_s[n0][N_NODE + m] * nom;
        ov1 += A_s[n1][N_NODE + m] * nom;
    }
    ii_s[n0][d] = iv0; ii_s[n1][d] = iv1;
    io_s[n0][d] = ov0; io_s[n1][d] = ov1;
    __syncthreads();

    // ---- P3 (fused gates): all operands from LDS, conflict-free/broadcast
    float r0 = b_ih[d] + b_hh[d],           r1 = r0;
    float i0 = b_ih[32 + d] + b_hh[32 + d], i1 = i0;
    float gn0 = b_ih[64 + d],               gn1 = gn0;
    float hn0 = b_hh[64 + d],               hn1 = hn0;
    #pragma unroll
    for (int k = 0; k < 32; ++k) {
        const float wri = wih_s[d][k],      wro = wih_s[d][32 + k];
        const float wii = wih_s[32 + d][k], wio = wih_s[32 + d][32 + k];
        const float wni = wih_s[64 + d][k], wno = wih_s[64 + d][32 + k];
        const float whr = whh_s[d][k];
        const float whi = whh_s[32 + d][k];
        const float whn = whh_s[64 + d][k];
        const float a0 = ii_s[n0][k], a1 = ii_s[n1][k];
        const float o0 = io_s[n0][k], o1 = io_s[n1][k];
        const float h0 = h_s[n0][k],  h1 = h_s[n1][k];
        r0  += a0 * wri + o0 * wro + h0 * whr;
        r1  += a1 * wri + o1 * wro + h1 * whr;
        i0  += a0 * wii + o0 * wio + h0 * whi;
        i1  += a1 * wii + o1 * wio + h1 * whi;
        gn0 += a0 * wni + o0 * wno;
        gn1 += a1 * wni + o1 * wno;
        hn0 += h0 * whn;
        hn1 += h1 * whn;
    }

    // ---- P4: GRU nonlinearity (in-register), h update
    float hv0, hv1;
    {
        const float rg0 = sigf(r0), ig0 = sigf(i0);
        const float x0  = gn0 + rg0 * hn0;
        const float e0  = __expf(2.0f * fabsf(x0));
        const float ng0 = copysignf(1.0f - 2.0f / (e0 + 1.0f), x0);
        hv0 = ng0 + ig0 * (h_s[n0][d] - ng0);
        const float rg1 = sigf(r1), ig1 = sigf(i1);
        const float x1  = gn1 + rg1 * hn1;
        const float e1  = __expf(2.0f * fabsf(x1));
        const float ng1 = copysignf(1.0f - 2.0f / (e1 + 1.0f), x1);
        hv1 = ng1 + ig1 * (h_s[n1][d] - ng1);
    }
    __syncthreads();                  // everyone done reading h/ii/io
    h_s[n0][d] = hv0;
    h_s[n1][d] = hv1;
    __syncthreads();                  // h_new visible

    // ---- P5: seq gather (into ni/no space) + last index
    for (int idx = tid; idx < L_SEQ * D_DIM; idx += 256) {
        const int t = idx >> 5, dd = idx & 31;
        const int a = alias_inputs[b * L_SEQ + t];
        const float v = h_s[a][dd];
        if (t < 16) ni_s[t][dd] = v;
        else        no_s[t - 16][dd] = v;
    }
    if (tid == 0) {
        int s = 0;
        for (int t = 0; t < L_SEQ; ++t) s += mask[b * L_SEQ + t];
        last_s = s - 1;
    }
    __syncthreads();

    // ---- P6: q1 = ht @ w1 + b1
    if (tid < D_DIM) {
        const int lt = last_s;
        const float* sl = (lt < 16) ? &ni_s[lt][0] : &no_s[lt - 16][0];
        float acc = b1[tid];
        #pragma unroll
        for (int k = 0; k < 32; ++k) acc += sl[k] * w1[k * 32 + tid];
        q1_s[tid] = acc;
    }
    __syncthreads();

    // ---- P7: alpha (tmp into ii/io space)
    for (int idx = tid; idx < L_SEQ * D_DIM; idx += 256) {
        const int t = idx >> 5, dd = idx & 31;
        const float* sp = (t < 16) ? &ni_s[t][0] : &no_s[t - 16][0];
        float q2 = b2[dd];
        #pragma unroll
        for (int k = 0; k < 32; ++k) q2 += sp[k] * w2[k * 32 + dd];
        const float val = sigf(q1_s[dd] + q2) * w3[dd];
        if (t < 16) ii_s[t][dd] = val;
        else        io_s[t - 16][dd] = val;
    }
    __syncthreads();
    if (tid < L_SEQ) {
        const float* tp = (tid < 16) ? &ii_s[tid][0] : &io_s[tid - 16][0];
        float a = 0.0f;
        #pragma unroll
        for (int dd = 0; dd < 32; ++dd) a += tp[dd];
        alpha_s[tid] = a * (float)mask[b * L_SEQ + tid];
    }
    __syncthreads();

    // ---- P8: s_g
    if (tid < D_DIM) {
        float acc = 0.0f;
        #pragma unroll
        for (int t = 0; t < L_SEQ; ++t) {
            const float sv = (t < 16) ? ni_s[t][tid] : no_s[t - 16][tid];
            acc += alpha_s[t] * sv;
        }
        sg_out[b * D_DIM + tid] = acc;
    }
}

// ---------------------------------------------------------------- kernel 2
// scores[b, v] = sum_d s_g[b,d] * emb[1+v, d]   (VERBATIM r9 score3)
__global__ __launch_bounds__(256) void score3_kernel(
    const float* __restrict__ sg,    // [4096, 32] f32 (ws)
    const float* __restrict__ emb,   // [50000, 32] f32
    float* __restrict__ out)         // [4096, 49999] f32
{
    __shared__ float eT[D_DIM][257];   // transposed emb tile
    const int tid = threadIdx.x;
    const int b0  = blockIdx.x * 16;
    const int v0  = blockIdx.y * 256;

    #pragma unroll
    for (int i = 0; i < 8; ++i) {
        const int f = i * 256 + tid;
        const int r = f >> 3, c = f & 7;
        int grow = 1 + v0 + r;
        if (grow > NV_OUT) grow = NV_OUT;
        const f32x4 ev = *reinterpret_cast<const f32x4*>(
            &emb[(size_t)grow * D_DIM + c * 4]);
        eT[c * 4 + 0][r] = ev[0];
        eT[c * 4 + 1][r] = ev[1];
        eT[c * 4 + 2][r] = ev[2];
        eT[c * 4 + 3][r] = ev[3];
    }
    __syncthreads();

    float e[32];
    #pragma unroll
    for (int k = 0; k < 32; ++k) e[k] = eT[k][tid];

    const int  v  = v0 + tid;
    const bool ok = (v < NV_OUT);

    #pragma unroll
    for (int r = 0; r < 16; ++r) {
        const float* sr = sg + (size_t)(b0 + r) * D_DIM;   // block-uniform
        float acc = 0.0f;
        #pragma unroll
        for (int k = 0; k < 32; ++k) acc += e[k] * sr[k];
        if (ok) out[(size_t)(b0 + r) * NV_OUT + v] = acc;
    }
}

// ---------------------------------------------------------------- launch
extern "C" void kernel_launch(void* const* d_in, const int* in_sizes, int n_in,
                              void* d_out, int out_size, void* d_ws, size_t ws_size,
                              hipStream_t stream)
{
    const int*   alias_inputs = (const int*)  d_in[0];
    const float* A      = (const float*)d_in[1];
    const int*   items  = (const int*)  d_in[2];
    const int*   mask   = (const int*)  d_in[3];
    const float* emb    = (const float*)d_in[4];
    const float* w_ih   = (const float*)d_in[5];
    const float* w_hh   = (const float*)d_in[6];
    const float* b_ih   = (const float*)d_in[7];
    const float* b_hh   = (const float*)d_in[8];
    const float* b_iah  = (const float*)d_in[9];
    const float* b_oah  = (const float*)d_in[10];
    const float* w_ein  = (const float*)d_in[11];
    const float* b_ein  = (const float*)d_in[12];
    const float* w_eout = (const float*)d_in[13];
    const float* b_eout = (const float*)d_in[14];
    const float* w1     = (const float*)d_in[15];
    const float* b1     = (const float*)d_in[16];
    const float* w2     = (const float*)d_in[17];
    const float* b2     = (const float*)d_in[18];
    const float* w3     = (const float*)d_in[19];

    float* sg  = (float*)d_ws;                     // 4096*32 f32
    float* out = (float*)d_out;                    // FP32 output

    hipLaunchKernelGGL(session3_kernel, dim3(B_BATCH), dim3(256), 0, stream,
                       alias_inputs, A, items, mask, emb,
                       w_ih, w_hh, b_ih, b_hh, b_iah, b_oah,
                       w_ein, b_ein, w_eout, b_eout,
                       w1, b1, w2, b2, w3, sg);

    const int nvt = (NV_OUT + 255) / 256;   // 196
    hipLaunchKernelGGL(score3_kernel, dim3(B_BATCH / 16, nvt), dim3(256), 0, stream,
                       sg, emb, out);
}